// Round 5
// baseline (285.674 us; speedup 1.0000x reference)
//
#include <hip/hip_runtime.h>

#define BATCH 16
#define LQ    1024
#define LK    1024
#define DD    512

typedef unsigned int u32;
typedef short short8 __attribute__((ext_vector_type(8)));
typedef float f32x4 __attribute__((ext_vector_type(4)));
typedef u32 u32x2 __attribute__((ext_vector_type(2)));
typedef u32 u32x4 __attribute__((ext_vector_type(4)));
#define AS1 __attribute__((address_space(1)))
#define AS3 __attribute__((address_space(3)))

// ---------------------------------------------------------------------------
// split fp32 pair -> packed bf16 hi (truncation) and bf16 lo (= x - hi)
// ---------------------------------------------------------------------------
__device__ __forceinline__ void split2(float x0, float x1, u32& hp, u32& lp) {
    u32 u0 = __float_as_uint(x0), u1 = __float_as_uint(x1);
    hp = __builtin_amdgcn_perm(u1, u0, 0x07060302u);   // (bf16(x0), bf16(x1))
    float l0 = x0 - __uint_as_float(u0 & 0xffff0000u);
    float l1 = x1 - __uint_as_float(u1 & 0xffff0000u);
    lp = __builtin_amdgcn_perm(__float_as_uint(l1), __float_as_uint(l0), 0x07060302u);
}

__device__ __forceinline__ void mk_frags(f32x4 f0, f32x4 f1, short8& h, short8& l) {
    union { u32 u[4]; short8 s; } H, L;
    split2(f0[0], f0[1], H.u[0], L.u[0]);
    split2(f0[2], f0[3], H.u[1], L.u[1]);
    split2(f1[0], f1[1], H.u[2], L.u[2]);
    split2(f1[2], f1[3], H.u[3], L.u[3]);
    h = H.s; l = L.s;
}

// hi-only variant (4 perms, no lo)
__device__ __forceinline__ short8 hi8(f32x4 f0, f32x4 f1) {
    union { u32 u[4]; short8 s; } H;
    H.u[0] = __builtin_amdgcn_perm(__float_as_uint(f0[1]), __float_as_uint(f0[0]), 0x07060302u);
    H.u[1] = __builtin_amdgcn_perm(__float_as_uint(f0[3]), __float_as_uint(f0[2]), 0x07060302u);
    H.u[2] = __builtin_amdgcn_perm(__float_as_uint(f1[1]), __float_as_uint(f1[0]), 0x07060302u);
    H.u[3] = __builtin_amdgcn_perm(__float_as_uint(f1[3]), __float_as_uint(f1[2]), 0x07060302u);
    return H.s;
}

// Packed hi/lo layout for a logical [R x K] fp32 matrix (same byte count):
// per row, per 32-k chunk: 16 u32 of hi pairs (k ascending), then 16 u32 of lo.

// ---------------------------------------------------------------------------
// Q [16384 x 512] fp32 -> packed hi/lo. 64 threads/row, 8 floats/thread.
// ---------------------------------------------------------------------------
__global__ __launch_bounds__(256) void pack_q(const float* __restrict__ Q,
                                              float* __restrict__ Qhl) {
    const int idx = blockIdx.x * 256 + threadIdx.x;
    const int row = idx >> 6, u = idx & 63;
    const float* src = Q + (size_t)row * DD + u * 8;
    f32x4 a = *(const f32x4*)src;
    f32x4 b = *(const f32x4*)(src + 4);
    u32 h0, h1, h2, h3, l0, l1, l2, l3;
    split2(a[0], a[1], h0, l0);
    split2(a[2], a[3], h1, l1);
    split2(b[0], b[1], h2, l2);
    split2(b[2], b[3], h3, l3);
    u32* dst = (u32*)Qhl + (size_t)row * DD + (u >> 2) * 32 + (u & 3) * 4;
    *(u32x4*)dst        = u32x4{h0, h1, h2, h3};
    *(u32x4*)(dst + 16) = u32x4{l0, l1, l2, l3};
}

// ---------------------------------------------------------------------------
// V [LK x DD] -> packed Vhl [LK x DD] and packed Vthl [DD x LK], per batch.
// ---------------------------------------------------------------------------
__global__ __launch_bounds__(256) void transpose_pack_v(const float* __restrict__ V,
                                                        float* __restrict__ Vhl,
                                                        float* __restrict__ Vthl) {
    __shared__ float tile[32][33];
    const int b = blockIdx.z;
    const int c0 = blockIdx.x * 32;   // d
    const int r0 = blockIdx.y * 32;   // kv
    const int t = threadIdx.x;
    const int r = t >> 3, c4 = (t & 7) * 4;
    const float* Vb = V + (size_t)b * LK * DD;
    f32x4 f = *(const f32x4*)(Vb + (size_t)(r0 + r) * DD + c0 + c4);

    u32 h0, l0, h1, l1;
    split2(f[0], f[1], h0, l0);
    split2(f[2], f[3], h1, l1);
    u32* vb = (u32*)Vhl + (size_t)b * LK * DD + (size_t)(r0 + r) * DD
            + (c0 >> 5) * 32 + (t & 7) * 2;
    *(u32x2*)vb        = u32x2{h0, h1};
    *(u32x2*)(vb + 16) = u32x2{l0, l1};

    tile[r][c4 + 0] = f[0]; tile[r][c4 + 1] = f[1];
    tile[r][c4 + 2] = f[2]; tile[r][c4 + 3] = f[3];
    __syncthreads();

    const int n = t >> 3, k4 = (t & 7) * 4;
    f32x4 o = {tile[k4 + 0][n], tile[k4 + 1][n], tile[k4 + 2][n], tile[k4 + 3][n]};
    split2(o[0], o[1], h0, l0);
    split2(o[2], o[3], h1, l1);
    u32* vtb = (u32*)Vthl + (size_t)b * DD * LK + (size_t)(c0 + n) * LK
             + (r0 >> 5) * 32 + (t & 7) * 2;
    *(u32x2*)vtb        = u32x2{h0, h1};
    *(u32x2*)(vtb + 16) = u32x2{l0, l1};
}

// ---------------------------------------------------------------------------
// 8-phase-style 256-class split-bf16 GEMM (HK/m201-derived schedule):
//   C[1024 x NG] = A[1024 x KG] * B[NG x KG]^T  per batch
// BM x BN tile, BK=32 logical k (=128 B/row packed or fp32), 8 waves (512 thr),
// double-buffered LDS, NPH = BM/64 phases per K-tile. Per phase:
//   {ds_read frags  ||  (phase 0: issue all next-tile global_load_lds)}
//   s_barrier ; s_waitcnt lgkmcnt(0) ; sched_barrier
//   setprio(1) ; MFMA cluster ; setprio(0) ; s_barrier
// Tile end: s_waitcnt vmcnt(0) (loads issued ~NPH phases earlier -> hidden) ;
// s_barrier ; swap buffers. Counted-wait discipline: vmcnt never drains
// mid-tile; loads stay in flight across all compute phases.
//   APACKED=1: A pre-packed hi/lo (zero VALU in MFMA region)
//   APACKED=0: A raw fp32; frags built in-phase (NPROD=2 -> 8 perms/phase)
//   NPROD=3: Ah*Bh + Ah*Bl + Al*Bh ; NPROD=2: Ah*Bh + Ah*Bl
// LDS swizzle: rows of 8 x 16B chunks, phys chunk = logical ^ (row&7);
// staging source pre-swizzled per-thread, LDS dest linear (m104-safe).
// XCD swizzle bijective (nwg % 8 == 0).
// ---------------------------------------------------------------------------
template <int KG, int NG, int BM, int BN, int NPROD, int APACKED>
__global__ __launch_bounds__(512, 2) void gemm256(const float* __restrict__ A,
                                                  const float* __restrict__ B,
                                                  float* __restrict__ C) {
    constexpr int NI   = BM / 32;       // a-frags per wave (wave rows = BM/2)
    constexpr int NJ   = BN / 64;       // b-frags per wave (wave cols = BN/4) = 4
    constexpr int NPH  = NI / 2;        // phases per K-tile
    constexpr int ARND = BM / 64;       // staging rounds for A
    constexpr int BRND = BN / 64;       // staging rounds for B
    constexpr int NT   = KG / 32;       // K-tiles

    __shared__ float smA[2][BM * 32];
    __shared__ float smB[2][BN * 32];

    constexpr int GX = 1024 / BM, GYY = NG / BN;
    constexpr u32 nwg = (u32)(GX * GYY * BATCH);
    const u32 wgid = blockIdx.x + blockIdx.y * GX + blockIdx.z * (GX * GYY);
    const u32 swz  = (wgid & 7) * (nwg / 8) + (wgid >> 3);
    const int bm0  = (int)(swz % GX) * BM;
    const int bn0  = (int)((swz / GX) % GYY) * BN;
    const int b    = (int)(swz / (GX * GYY));

    const int tid = threadIdx.x;
    const int w = tid >> 6, lane = tid & 63;
    const int mf = lane & 15, q = lane >> 4, e = mf & 7;
    const int ch = ((q) ^ e) * 4;            // packed hi subchunk q
    const int cl = ((4 + q) ^ e) * 4;        // packed lo subchunk q
    const int c0 = ((2 * q) ^ e) * 4;        // raw fp32 logical chunk 2q
    const int c1 = ((2 * q + 1) ^ e) * 4;    // raw fp32 logical chunk 2q+1
    const int wmL = (w >> 2) * (BM / 2);     // wave row origin (2 M-waves)
    const int wnL = (w & 3) * 64;            // wave col origin (4 N-waves)

    // staging map: thread covers row (r*64 + tid>>3), phys chunk (tid&7)
    const int rowoff = tid >> 3;
    const int ckoff  = ((tid & 7) ^ ((tid >> 3) & 7)) * 4;   // logical chunk, u32
    const u32* Ag = (const u32*)A + (size_t)b * 1024 * KG + (size_t)(bm0 + rowoff) * KG + ckoff;
    const u32* Bg = (const u32*)B + (size_t)b * NG * KG   + (size_t)(bn0 + rowoff) * KG + ckoff;

    f32x4 acc[NI][NJ] = {};

    auto stage = [&](int pb, int kc) {
        const u32* ag = Ag + kc * 32;
        const u32* bg = Bg + kc * 32;
#pragma unroll
        for (int r = 0; r < ARND; ++r)
            __builtin_amdgcn_global_load_lds((const AS1 u32*)(ag + (size_t)r * 64 * KG),
                                             (AS3 u32*)(&smA[pb][(r * 512 + tid) * 4]), 16, 0, 0);
#pragma unroll
        for (int r = 0; r < BRND; ++r)
            __builtin_amdgcn_global_load_lds((const AS1 u32*)(bg + (size_t)r * 64 * KG),
                                             (AS3 u32*)(&smB[pb][(r * 512 + tid) * 4]), 16, 0, 0);
    };

    stage(0, 0);
    asm volatile("s_waitcnt vmcnt(0)" ::: "memory");
    __builtin_amdgcn_s_barrier();

    int p = 0;
    for (int kc = 0; kc < NT; ++kc) {
        const float* As = &smA[p][0];
        const float* Bs = &smB[p][0];
        short8 bh[NJ], bl[NJ];
#pragma unroll
        for (int qp = 0; qp < NPH; ++qp) {
            if (qp == 0 && kc + 1 < NT) stage(p ^ 1, kc + 1);
            if (qp == 0) {
#pragma unroll
                for (int j = 0; j < NJ; ++j) {
                    const int rb = (wnL + mf + j * 16) * 32;
                    bh[j] = *(const short8*)&Bs[rb + ch];
                    bl[j] = *(const short8*)&Bs[rb + cl];
                }
            }
            short8 a_h[2], a_l[2];
#pragma unroll
            for (int ii = 0; ii < 2; ++ii) {
                const int ra = (wmL + mf + (qp * 2 + ii) * 16) * 32;
                if constexpr (APACKED) {
                    a_h[ii] = *(const short8*)&As[ra + ch];
                    if constexpr (NPROD == 3) a_l[ii] = *(const short8*)&As[ra + cl];
                } else {
                    f32x4 f0 = *(const f32x4*)&As[ra + c0];
                    f32x4 f1 = *(const f32x4*)&As[ra + c1];
                    if constexpr (NPROD == 3) mk_frags(f0, f1, a_h[ii], a_l[ii]);
                    else                      a_h[ii] = hi8(f0, f1);
                }
            }
            __builtin_amdgcn_s_barrier();
            asm volatile("s_waitcnt lgkmcnt(0)" ::: "memory");
            __builtin_amdgcn_sched_barrier(0);
            __builtin_amdgcn_s_setprio(1);
#pragma unroll
            for (int ii = 0; ii < 2; ++ii)
#pragma unroll
                for (int j = 0; j < NJ; ++j) {
                    const int i = qp * 2 + ii;
                    acc[i][j] = __builtin_amdgcn_mfma_f32_16x16x32_bf16(a_h[ii], bh[j], acc[i][j], 0, 0, 0);
                    acc[i][j] = __builtin_amdgcn_mfma_f32_16x16x32_bf16(a_h[ii], bl[j], acc[i][j], 0, 0, 0);
                    if constexpr (NPROD == 3)
                        acc[i][j] = __builtin_amdgcn_mfma_f32_16x16x32_bf16(a_l[ii], bh[j], acc[i][j], 0, 0, 0);
                }
            __builtin_amdgcn_s_setprio(0);
            __builtin_amdgcn_s_barrier();
        }
        asm volatile("s_waitcnt vmcnt(0)" ::: "memory");
        __builtin_amdgcn_s_barrier();
        p ^= 1;
    }

    // epilogue: C/D layout col = lane&15, row = q*4 + reg  [m89-verified]
    float* Cb = C + (size_t)b * 1024 * NG + (size_t)bm0 * NG + bn0;
#pragma unroll
    for (int i = 0; i < NI; ++i)
#pragma unroll
        for (int j = 0; j < NJ; ++j)
#pragma unroll
            for (int r = 0; r < 4; ++r)
                Cb[(size_t)(wmL + i * 16 + q * 4 + r) * NG + wnL + j * 16 + mf] = acc[i][j][r];
}

// ---------------------------------------------------------------------------
// Barrier-free row softmax in place: one wave per row, 4 rows/block.
// ---------------------------------------------------------------------------
__global__ __launch_bounds__(256) void softmax_rows2(float* __restrict__ S) {
    const int t = threadIdx.x;
    const int wave = t >> 6, lane = t & 63;
    const size_t row = (size_t)blockIdx.x * 4 + wave;
    float* p = S + row * LK;
    f32x4 v[4];
#pragma unroll
    for (int c = 0; c < 4; ++c)
        v[c] = *(const f32x4*)(p + lane * 4 + c * 256);
    float m = -1e30f;
#pragma unroll
    for (int c = 0; c < 4; ++c)
        m = fmaxf(m, fmaxf(fmaxf(v[c][0], v[c][1]), fmaxf(v[c][2], v[c][3])));
#pragma unroll
    for (int off = 1; off < 64; off <<= 1) m = fmaxf(m, __shfl_xor(m, off, 64));
    float s = 0.0f;
#pragma unroll
    for (int c = 0; c < 4; ++c) {
        v[c][0] = __expf(v[c][0] - m);
        v[c][1] = __expf(v[c][1] - m);
        v[c][2] = __expf(v[c][2] - m);
        v[c][3] = __expf(v[c][3] - m);
        s += (v[c][0] + v[c][1]) + (v[c][2] + v[c][3]);
    }
#pragma unroll
    for (int off = 1; off < 64; off <<= 1) s += __shfl_xor(s, off, 64);
    const float inv = 1.0f / s;
#pragma unroll
    for (int c = 0; c < 4; ++c) {
        v[c] = v[c] * inv;
        *(f32x4*)(p + lane * 4 + c * 256) = v[c];
    }
}

// ===========================================================================
// Fallback A (ws >= 67 MB): round-4 verified 128x128 2-phase path
// ===========================================================================
template <int KG, int NG, int NPROD, bool PACKA>
__global__ __launch_bounds__(256) void gemm_bf16split(const float* __restrict__ A,
                                                      const float* __restrict__ B,
                                                      float* __restrict__ C) {
    __shared__ float sm[2][2][128 * 32];
    constexpr int GY  = NG / 128;
    constexpr int GYS = (GY == 8) ? 3 : 2;
    const u32 wgid = blockIdx.x + (blockIdx.y << 3) + ((u32)blockIdx.z << (3 + GYS));
    const u32 nwg  = (u32)(8 * GY * BATCH);
    const u32 swz  = (wgid & 7) * (nwg >> 3) + (wgid >> 3);
    const int bm0  = (swz & 7) * 128;
    const int bn0  = ((swz >> 3) & (GY - 1)) * 128;
    const int b    = swz >> (3 + GYS);
    const int tid = threadIdx.x;
    const int w   = tid >> 6;
    const int lane = tid & 63;
    const int op   = w >> 1;
    const int woff = (w & 1) * 64;
    const float* gsrc = (op == 0)
        ? A + (size_t)b * 1024 * KG + (size_t)(bm0 + woff) * KG
        : B + (size_t)b * NG * KG   + (size_t)(bn0 + woff) * KG;
    gsrc += (size_t)(lane >> 3) * KG + (size_t)(((lane & 7) ^ (lane >> 3)) * 4);
    const int mf = lane & 15, q = lane >> 4;
    const int e  = mf & 7;
    const int ch = ((q)     ^ e) * 4;
    const int cl = ((4 + q) ^ e) * 4;
    const int c0 = ((2 * q)     ^ e) * 4;
    const int c1 = ((2 * q + 1) ^ e) * 4;
    const int wm = (w & 1) * 64, wn = (w >> 1) * 64;
    f32x4 acc[4][4] = {};
    auto stage = [&](int pb, int k) {
#pragma unroll
        for (int t = 0; t < 8; ++t)
            __builtin_amdgcn_global_load_lds((const AS1 u32*)(gsrc + k + (size_t)t * 8 * KG),
                                             (AS3 u32*)(&sm[pb][op][(woff + t * 8) * 32]),
                                             16, 0, 0);
    };
    stage(0, 0);
    int p = 0;
    for (int k0 = 0; k0 < KG; k0 += 32) {
        __syncthreads();
        if (k0 + 32 < KG) stage(p ^ 1, k0 + 32);
        const float* As = &sm[p][0][0];
        const float* Bs = &sm[p][1][0];
        short8 ah[4], al[4], bh[4], bl[4];
#pragma unroll
        for (int i = 0; i < 4; ++i) {
            const int ra = (wm + mf + i * 16) * 32;
            if constexpr (PACKA) {
                ah[i] = *(const short8*)&As[ra + ch];
                if constexpr (NPROD == 3) al[i] = *(const short8*)&As[ra + cl];
            } else {
                f32x4 f0 = *(const f32x4*)&As[ra + c0];
                f32x4 f1 = *(const f32x4*)&As[ra + c1];
                if constexpr (NPROD == 3) mk_frags(f0, f1, ah[i], al[i]);
                else                      ah[i] = hi8(f0, f1);
            }
            const int rb = (wn + mf + i * 16) * 32;
            bh[i] = *(const short8*)&Bs[rb + ch];
            bl[i] = *(const short8*)&Bs[rb + cl];
        }
#pragma unroll
        for (int i = 0; i < 4; ++i)
#pragma unroll
            for (int j = 0; j < 4; ++j) {
                acc[i][j] = __builtin_amdgcn_mfma_f32_16x16x32_bf16(ah[i], bh[j], acc[i][j], 0, 0, 0);
                acc[i][j] = __builtin_amdgcn_mfma_f32_16x16x32_bf16(ah[i], bl[j], acc[i][j], 0, 0, 0);
                if constexpr (NPROD == 3)
                    acc[i][j] = __builtin_amdgcn_mfma_f32_16x16x32_bf16(al[i], bh[j], acc[i][j], 0, 0, 0);
            }
        p ^= 1;
    }
    float* Cb = C + (size_t)b * 1024 * NG + (size_t)bm0 * NG + bn0;
#pragma unroll
    for (int i = 0; i < 4; ++i)
#pragma unroll
        for (int j = 0; j < 4; ++j)
#pragma unroll
            for (int r = 0; r < 4; ++r)
                Cb[(size_t)(wm + i * 16 + q * 4 + r) * NG + wn + j * 16 + mf] = acc[i][j][r];
}

// ===========================================================================
// Fallback B (tiny ws): plain fp32 tiled GEMMs + block softmax
// ===========================================================================
constexpr int BMf = 64, BNf = 64, BKf = 16, PADf = 4;

__global__ __launch_bounds__(256) void softmax_rows(float* __restrict__ S) {
    float* p = S + (size_t)blockIdx.x * LK;
    const int t = threadIdx.x;
    float4 v = *(float4*)(p + (t << 2));
    float m = fmaxf(fmaxf(v.x, v.y), fmaxf(v.z, v.w));
#pragma unroll
    for (int off = 1; off < 64; off <<= 1) m = fmaxf(m, __shfl_xor(m, off, 64));
    __shared__ float redm[4]; __shared__ float reds[4];
    const int wave = t >> 6, lane = t & 63;
    if (lane == 0) redm[wave] = m;
    __syncthreads();
    m = fmaxf(fmaxf(redm[0], redm[1]), fmaxf(redm[2], redm[3]));
    v.x = __expf(v.x - m); v.y = __expf(v.y - m);
    v.z = __expf(v.z - m); v.w = __expf(v.w - m);
    float s = (v.x + v.y) + (v.z + v.w);
#pragma unroll
    for (int off = 1; off < 64; off <<= 1) s += __shfl_xor(s, off, 64);
    if (lane == 0) reds[wave] = s;
    __syncthreads();
    s = (reds[0] + reds[1]) + (reds[2] + reds[3]);
    const float inv = 1.0f / s;
    v.x *= inv; v.y *= inv; v.z *= inv; v.w *= inv;
    *(float4*)(p + (t << 2)) = v;
}

__global__ __launch_bounds__(256) void gemm_qvt(const float* __restrict__ Q,
                                                const float* __restrict__ V,
                                                float* __restrict__ S) {
    __shared__ __align__(16) float sA[BKf][BMf + PADf];
    __shared__ __align__(16) float sB[BKf][BNf + PADf];
    const int b = blockIdx.z;
    const float* Qb = Q + (size_t)b * LQ * DD + (size_t)blockIdx.x * BMf * DD;
    const float* Vb = V + (size_t)b * LK * DD + (size_t)blockIdx.y * BNf * DD;
    float*       Sb = S + (size_t)b * LQ * LK;
    const int tid = threadIdx.x;
    const int tx = tid & 15, ty = tid >> 4;
    const int lr = tid >> 2, lc = (tid & 3) << 2;
    float acc[4][4] = {};
    for (int k0 = 0; k0 < DD; k0 += BKf) {
        float4 qa = *(const float4*)(Qb + (size_t)lr * DD + k0 + lc);
        float4 va = *(const float4*)(Vb + (size_t)lr * DD + k0 + lc);
        __syncthreads();
        sA[lc + 0][lr] = qa.x; sA[lc + 1][lr] = qa.y; sA[lc + 2][lr] = qa.z; sA[lc + 3][lr] = qa.w;
        sB[lc + 0][lr] = va.x; sB[lc + 1][lr] = va.y; sB[lc + 2][lr] = va.z; sB[lc + 3][lr] = va.w;
        __syncthreads();
#pragma unroll
        for (int k = 0; k < BKf; ++k) {
            float4 a4 = *(const float4*)&sA[k][ty << 2];
            float4 b4 = *(const float4*)&sB[k][tx << 2];
            float a[4] = {a4.x, a4.y, a4.z, a4.w};
            float bb[4] = {b4.x, b4.y, b4.z, b4.w};
#pragma unroll
            for (int i = 0; i < 4; ++i)
#pragma unroll
                for (int j = 0; j < 4; ++j) acc[i][j] = fmaf(a[i], bb[j], acc[i][j]);
        }
    }
    const int r0 = blockIdx.x * BMf + (ty << 2), c0 = blockIdx.y * BNf + (tx << 2);
#pragma unroll
    for (int i = 0; i < 4; ++i) {
        float4 o = {acc[i][0], acc[i][1], acc[i][2], acc[i][3]};
        *(float4*)(Sb + (size_t)(r0 + i) * LK + c0) = o;
    }
}

__global__ __launch_bounds__(256) void gemm_pv(const float* __restrict__ P,
                                               const float* __restrict__ V,
                                               float* __restrict__ C) {
    __shared__ __align__(16) float sA[BKf][BMf + PADf];
    __shared__ __align__(16) float sB[BKf][BNf + PADf];
    const int b = blockIdx.z;
    const float* Pb = P + (size_t)b * LQ * LK + (size_t)blockIdx.x * BMf * LK;
    const float* Vb = V + (size_t)b * LK * DD;
    float*       Cb = C + (size_t)b * LQ * DD;
    const int tid = threadIdx.x;
    const int tx = tid & 15, ty = tid >> 4;
    const int lr = tid >> 2, lc = (tid & 3) << 2;
    const int bkr = tid >> 4, bcg = (tid & 15) << 2;
    const int n0 = blockIdx.y * BNf;
    float acc[4][4] = {};
    for (int k0 = 0; k0 < LK; k0 += BKf) {
        float4 pa = *(const float4*)(Pb + (size_t)lr * LK + k0 + lc);
        float4 vb = *(const float4*)(Vb + (size_t)(k0 + bkr) * DD + n0 + bcg);
        __syncthreads();
        sA[lc + 0][lr] = pa.x; sA[lc + 1][lr] = pa.y; sA[lc + 2][lr] = pa.z; sA[lc + 3][lr] = pa.w;
        *(float4*)&sB[bkr][bcg] = vb;
        __syncthreads();
#pragma unroll
        for (int k = 0; k < BKf; ++k) {
            float4 a4 = *(const float4*)&sA[k][ty << 2];
            float4 b4 = *(const float4*)&sB[k][tx << 2];
            float a[4] = {a4.x, a4.y, a4.z, a4.w};
            float bb[4] = {b4.x, b4.y, b4.z, b4.w};
#pragma unroll
            for (int i = 0; i < 4; ++i)
#pragma unroll
                for (int j = 0; j < 4; ++j) acc[i][j] = fmaf(a[i], bb[j], acc[i][j]);
        }
    }
    const int r0 = blockIdx.x * BMf + (ty << 2), c0 = n0 + (tx << 2);
#pragma unroll
    for (int i = 0; i < 4; ++i) {
        float4 o = {acc[i][0], acc[i][1], acc[i][2], acc[i][3]};
        *(float4*)(Cb + (size_t)(r0 + i) * DD + c0) = o;
    }
}

// ---------------------------------------------------------------------------
extern "C" void kernel_launch(void* const* d_in, const int* in_sizes, int n_in,
                              void* d_out, int out_size, void* d_ws, size_t ws_size,
                              hipStream_t stream) {
    const float* Q = (const float*)d_in[0];
    const float* V = (const float*)d_in[1];

    float* ctx  = (float*)d_out;                       // [16,1024,512]
    float* attn = ctx + (size_t)BATCH * LQ * DD;       // [16,1024,1024]

    const size_t qv_elems = (size_t)BATCH * LQ * DD;   // 8.4M floats = 33.55 MB
    const size_t need256  = 3 * qv_elems * sizeof(float);   // Qhl+Vhl+Vthl = 100.7 MB
    const size_t need128  = 2 * qv_elems * sizeof(float);   // Vhl+Vthl = 67.1 MB

    if (ws_size >= need256) {
        float* Qhl  = (float*)d_ws;
        float* Vhl  = Qhl + qv_elems;
        float* Vthl = Vhl + qv_elems;
        pack_q<<<dim3(BATCH * LQ * DD / (8 * 256)), 256, 0, stream>>>(Q, Qhl);
        transpose_pack_v<<<dim3(DD / 32, LK / 32, BATCH), 256, 0, stream>>>(V, Vhl, Vthl);
        // S = Q @ V^T : 256x256 tile, both operands packed, full 3-product
        gemm256<DD, LK, 256, 256, 3, 1><<<dim3(4, 4, BATCH), 512, 0, stream>>>(Qhl, Vhl, attn);
        softmax_rows2<<<dim3(BATCH * LQ / 4), 256, 0, stream>>>(attn);
        // ctx = P @ V : 128x256 tile, A raw fp32 (hi in-phase), 2-product
        gemm256<LK, DD, 128, 256, 2, 0><<<dim3(8, 2, BATCH), 512, 0, stream>>>(attn, Vthl, ctx);
    } else if (ws_size >= need128) {
        float* Vhl  = (float*)d_ws;
        float* Vthl = Vhl + qv_elems;
        transpose_pack_v<<<dim3(DD / 32, LK / 32, BATCH), 256, 0, stream>>>(V, Vhl, Vthl);
        gemm_bf16split<DD, LK, 3, false><<<dim3(8, 8, BATCH), 256, 0, stream>>>(Q, Vhl, attn);
        softmax_rows2<<<dim3(BATCH * LQ / 4), 256, 0, stream>>>(attn);
        gemm_bf16split<LK, DD, 2, false><<<dim3(8, 4, BATCH), 256, 0, stream>>>(attn, Vthl, ctx);
    } else {
        gemm_qvt<<<dim3(LQ / BMf, LK / BNf, BATCH), 256, 0, stream>>>(Q, V, attn);
        softmax_rows<<<dim3(BATCH * LQ), 256, 0, stream>>>(attn);
        gemm_pv<<<dim3(LQ / BMf, DD / BNf, BATCH), 256, 0, stream>>>(attn, V, ctx);
    }
}

// Round 6
// 269.562 us; speedup vs baseline: 1.0598x; 1.0598x over previous
//
#include <hip/hip_runtime.h>

#define BATCH 16
#define LQ    1024
#define LK    1024
#define DD    512

typedef unsigned int u32;
typedef short short8 __attribute__((ext_vector_type(8)));
typedef float f32x4 __attribute__((ext_vector_type(4)));
typedef u32 u32x2 __attribute__((ext_vector_type(2)));
typedef u32 u32x4 __attribute__((ext_vector_type(4)));
#define AS1 __attribute__((address_space(1)))
#define AS3 __attribute__((address_space(3)))

// ---------------------------------------------------------------------------
// split fp32 pair -> packed bf16 hi (truncation) and bf16 lo (= x - hi)
// ---------------------------------------------------------------------------
__device__ __forceinline__ void split2(float x0, float x1, u32& hp, u32& lp) {
    u32 u0 = __float_as_uint(x0), u1 = __float_as_uint(x1);
    hp = __builtin_amdgcn_perm(u1, u0, 0x07060302u);   // (bf16(x0), bf16(x1))
    float l0 = x0 - __uint_as_float(u0 & 0xffff0000u);
    float l1 = x1 - __uint_as_float(u1 & 0xffff0000u);
    lp = __builtin_amdgcn_perm(__float_as_uint(l1), __float_as_uint(l0), 0x07060302u);
}

__device__ __forceinline__ void mk_frags(f32x4 f0, f32x4 f1, short8& h, short8& l) {
    union { u32 u[4]; short8 s; } H, L;
    split2(f0[0], f0[1], H.u[0], L.u[0]);
    split2(f0[2], f0[3], H.u[1], L.u[1]);
    split2(f1[0], f1[1], H.u[2], L.u[2]);
    split2(f1[2], f1[3], H.u[3], L.u[3]);
    h = H.s; l = L.s;
}

// hi-only variant (4 perms, no lo)
__device__ __forceinline__ short8 hi8(f32x4 f0, f32x4 f1) {
    union { u32 u[4]; short8 s; } H;
    H.u[0] = __builtin_amdgcn_perm(__float_as_uint(f0[1]), __float_as_uint(f0[0]), 0x07060302u);
    H.u[1] = __builtin_amdgcn_perm(__float_as_uint(f0[3]), __float_as_uint(f0[2]), 0x07060302u);
    H.u[2] = __builtin_amdgcn_perm(__float_as_uint(f1[1]), __float_as_uint(f1[0]), 0x07060302u);
    H.u[3] = __builtin_amdgcn_perm(__float_as_uint(f1[3]), __float_as_uint(f1[2]), 0x07060302u);
    return H.s;
}

// Packed hi/lo layout for a logical [R x K] fp32 matrix (same byte count):
// per row, per 32-k chunk: 16 u32 of hi pairs (k ascending), then 16 u32 of lo.

// ---------------------------------------------------------------------------
// Q [16384 x 512] fp32 -> packed hi/lo. 64 threads/row, 8 floats/thread.
// ---------------------------------------------------------------------------
__global__ __launch_bounds__(256) void pack_q(const float* __restrict__ Q,
                                              float* __restrict__ Qhl) {
    const int idx = blockIdx.x * 256 + threadIdx.x;
    const int row = idx >> 6, u = idx & 63;
    const float* src = Q + (size_t)row * DD + u * 8;
    f32x4 a = *(const f32x4*)src;
    f32x4 b = *(const f32x4*)(src + 4);
    u32 h0, h1, h2, h3, l0, l1, l2, l3;
    split2(a[0], a[1], h0, l0);
    split2(a[2], a[3], h1, l1);
    split2(b[0], b[1], h2, l2);
    split2(b[2], b[3], h3, l3);
    u32* dst = (u32*)Qhl + (size_t)row * DD + (u >> 2) * 32 + (u & 3) * 4;
    *(u32x4*)dst        = u32x4{h0, h1, h2, h3};
    *(u32x4*)(dst + 16) = u32x4{l0, l1, l2, l3};
}

// ---------------------------------------------------------------------------
// V [LK x DD] -> packed Vhl [LK x DD] and packed Vthl [DD x LK], per batch.
// ---------------------------------------------------------------------------
__global__ __launch_bounds__(256) void transpose_pack_v(const float* __restrict__ V,
                                                        float* __restrict__ Vhl,
                                                        float* __restrict__ Vthl) {
    __shared__ float tile[32][33];
    const int b = blockIdx.z;
    const int c0 = blockIdx.x * 32;   // d
    const int r0 = blockIdx.y * 32;   // kv
    const int t = threadIdx.x;
    const int r = t >> 3, c4 = (t & 7) * 4;
    const float* Vb = V + (size_t)b * LK * DD;
    f32x4 f = *(const f32x4*)(Vb + (size_t)(r0 + r) * DD + c0 + c4);

    u32 h0, l0, h1, l1;
    split2(f[0], f[1], h0, l0);
    split2(f[2], f[3], h1, l1);
    u32* vb = (u32*)Vhl + (size_t)b * LK * DD + (size_t)(r0 + r) * DD
            + (c0 >> 5) * 32 + (t & 7) * 2;
    *(u32x2*)vb        = u32x2{h0, h1};
    *(u32x2*)(vb + 16) = u32x2{l0, l1};

    tile[r][c4 + 0] = f[0]; tile[r][c4 + 1] = f[1];
    tile[r][c4 + 2] = f[2]; tile[r][c4 + 3] = f[3];
    __syncthreads();

    const int n = t >> 3, k4 = (t & 7) * 4;
    f32x4 o = {tile[k4 + 0][n], tile[k4 + 1][n], tile[k4 + 2][n], tile[k4 + 3][n]};
    split2(o[0], o[1], h0, l0);
    split2(o[2], o[3], h1, l1);
    u32* vtb = (u32*)Vthl + (size_t)b * DD * LK + (size_t)(c0 + n) * LK
             + (r0 >> 5) * 32 + (t & 7) * 2;
    *(u32x2*)vtb        = u32x2{h0, h1};
    *(u32x2*)(vtb + 16) = u32x2{l0, l1};
}

// ---------------------------------------------------------------------------
// 4-phase counted-vmcnt split-bf16 GEMM (m201/T3+T4-derived, addressing
// verified by round-5 refcheck):  C[1024 x NG] = A[1024 x KG] * B[NG x KG]^T
// BM=256 fixed, BN in {256,128}. 8 waves (2M x 4N), double-buffered LDS.
// Per K-tile (BK=32 logical k = 128 B/row), 4 phases; phase qp consumes
// A-stages {0,2} (qp<2) or {1,3} (qp>=2); B consumed at qp==0.
// Next-tile staging is SPREAD: qp0 -> B0B1, qp1 -> B2B3 (if BN=256),
// qp2 -> A0A2, qp3 -> A1A3.  Counted waits (never vmcnt(0) mid-loop):
//   qp1-end: vmcnt(4|2) -> prev tile's late A-stages landed (phase-2 data)
//   qp3-end: vmcnt(2)   -> next tile's B + early A landed; late A in flight
// Soundness: all waves issue the same load sequence; per-wave vmcnt(N) at a
// barrier => all loads older than the N newest are LDS-visible to all waves.
//   APACKED=1: A pre-packed hi/lo. APACKED=0: A raw fp32, frags via perm.
//   NPROD=3: Ah*Bh+Ah*Bl+Al*Bh ; NPROD=2: Ah*Bh+Ah*Bl (P in [0,1]).
// LDS swizzle: rows of 8 x 16B chunks, phys chunk = logical ^ (row&7).
// XCD swizzle bijective (nwg == 256, % 8 == 0).
// ---------------------------------------------------------------------------
template <int KG, int NG, int BN, int NPROD, int APACKED>
__global__ __launch_bounds__(512, 2) void gemm4ph(const float* __restrict__ A,
                                                  const float* __restrict__ B,
                                                  float* __restrict__ C) {
    constexpr int BM   = 256;
    constexpr int NI   = 8;             // a-frags per wave (128 rows)
    constexpr int NJ   = BN / 64;       // b-frags per wave (BN/4 cols)
    constexpr int BRND = BN / 64;       // B staging rounds (64 rows each)
    constexpr int NT   = KG / 32;       // K-tiles

    __shared__ float smA[2][BM * 32];
    __shared__ float smB[2][BN * 32];

    constexpr int GX = 1024 / BM, GYY = NG / BN;
    constexpr u32 nwg = (u32)(GX * GYY * BATCH);
    const u32 wgid = blockIdx.x + blockIdx.y * GX + blockIdx.z * (GX * GYY);
    const u32 swz  = (wgid & 7) * (nwg / 8) + (wgid >> 3);
    const int bm0  = (int)(swz % GX) * BM;
    const int bn0  = (int)((swz / GX) % GYY) * BN;
    const int b    = (int)(swz / (GX * GYY));

    const int tid = threadIdx.x;
    const int w = tid >> 6, lane = tid & 63;
    const int mf = lane & 15, q = lane >> 4, e = mf & 7;
    const int ch = ((q) ^ e) * 4;            // packed hi subchunk q
    const int cl = ((4 + q) ^ e) * 4;        // packed lo subchunk q
    const int c0 = ((2 * q) ^ e) * 4;        // raw fp32 logical chunk 2q
    const int c1 = ((2 * q + 1) ^ e) * 4;    // raw fp32 logical chunk 2q+1
    const int wmL = (w >> 2) * (BM / 2);     // wave row origin (2 M-waves)
    const int wnL = (w & 3) * (BN / 4);      // wave col origin (4 N-waves)

    // staging map: thread covers row (r*64 + tid>>3), phys chunk (tid&7)
    const int rowoff = tid >> 3;
    const int ckoff  = ((tid & 7) ^ ((tid >> 3) & 7)) * 4;   // logical chunk, u32
    const u32* Ag = (const u32*)A + (size_t)b * 1024 * KG + (size_t)(bm0 + rowoff) * KG + ckoff;
    const u32* Bg = (const u32*)B + (size_t)b * NG * KG   + (size_t)(bn0 + rowoff) * KG + ckoff;

    f32x4 acc[NI][NJ] = {};

    auto issueB = [&](int pb, int kc, int r0) {
        const u32* bg = Bg + kc * 32;
#pragma unroll
        for (int r = 0; r < 2; ++r)
            __builtin_amdgcn_global_load_lds((const AS1 u32*)(bg + (size_t)(r0 + r) * 64 * KG),
                                             (AS3 u32*)(&smB[pb][((r0 + r) * 512 + tid) * 4]), 16, 0, 0);
    };
    auto issueA = [&](int pb, int kc, int ra, int rb) {
        const u32* ag = Ag + kc * 32;
        __builtin_amdgcn_global_load_lds((const AS1 u32*)(ag + (size_t)ra * 64 * KG),
                                         (AS3 u32*)(&smA[pb][(ra * 512 + tid) * 4]), 16, 0, 0);
        __builtin_amdgcn_global_load_lds((const AS1 u32*)(ag + (size_t)rb * 64 * KG),
                                         (AS3 u32*)(&smA[pb][(rb * 512 + tid) * 4]), 16, 0, 0);
    };

    // prologue: full tile 0, drain once (only vmcnt(0) in the kernel body)
    issueB(0, 0, 0);
    if constexpr (BRND == 4) issueB(0, 0, 2);
    issueA(0, 0, 0, 2);
    issueA(0, 0, 1, 3);
    asm volatile("s_waitcnt vmcnt(0)" ::: "memory");
    __builtin_amdgcn_s_barrier();

    int p = 0;
    for (int kc = 0; kc < NT; ++kc) {
        const bool more = (kc + 1 < NT);
        const float* As = &smA[p][0];
        const float* Bs = &smB[p][0];
        short8 bh[NJ], bl[NJ];
#pragma unroll
        for (int qp = 0; qp < 4; ++qp) {
            // ---- read section (buf p) ----
            if (qp == 0) {
#pragma unroll
                for (int j = 0; j < NJ; ++j) {
                    const int rb = (wnL + mf + j * 16) * 32;
                    bh[j] = *(const short8*)&Bs[rb + ch];
                    bl[j] = *(const short8*)&Bs[rb + cl];
                }
            }
            short8 a_h[2], a_l[2];
#pragma unroll
            for (int ii = 0; ii < 2; ++ii) {
                const int ra = (wmL + mf + (qp * 2 + ii) * 16) * 32;
                if constexpr (APACKED) {
                    a_h[ii] = *(const short8*)&As[ra + ch];
                    if constexpr (NPROD == 3) a_l[ii] = *(const short8*)&As[ra + cl];
                } else {
                    f32x4 f0 = *(const f32x4*)&As[ra + c0];
                    f32x4 f1 = *(const f32x4*)&As[ra + c1];
                    if constexpr (NPROD == 3) mk_frags(f0, f1, a_h[ii], a_l[ii]);
                    else                      a_h[ii] = hi8(f0, f1);
                }
            }
            // ---- spread staging for next tile into buf p^1 ----
            if (more) {
                if (qp == 0) issueB(p ^ 1, kc + 1, 0);
                if (qp == 1) { if constexpr (BRND == 4) issueB(p ^ 1, kc + 1, 2); }
                if (qp == 2) issueA(p ^ 1, kc + 1, 0, 2);
                if (qp == 3) issueA(p ^ 1, kc + 1, 1, 3);
            }
            // ---- compute section ----
            __builtin_amdgcn_s_barrier();
            asm volatile("s_waitcnt lgkmcnt(0)" ::: "memory");
            __builtin_amdgcn_sched_barrier(0);
            __builtin_amdgcn_s_setprio(1);
#pragma unroll
            for (int ii = 0; ii < 2; ++ii)
#pragma unroll
                for (int j = 0; j < NJ; ++j) {
                    const int i = qp * 2 + ii;
                    acc[i][j] = __builtin_amdgcn_mfma_f32_16x16x32_bf16(a_h[ii], bh[j], acc[i][j], 0, 0, 0);
                    acc[i][j] = __builtin_amdgcn_mfma_f32_16x16x32_bf16(a_h[ii], bl[j], acc[i][j], 0, 0, 0);
                    if constexpr (NPROD == 3)
                        acc[i][j] = __builtin_amdgcn_mfma_f32_16x16x32_bf16(a_l[ii], bh[j], acc[i][j], 0, 0, 0);
                }
            __builtin_amdgcn_s_setprio(0);
            // ---- counted waits (before trailing barrier) ----
            if (qp == 1) {
                if (more) {
                    if constexpr (BRND == 4) asm volatile("s_waitcnt vmcnt(4)" ::: "memory");
                    else                     asm volatile("s_waitcnt vmcnt(2)" ::: "memory");
                } else {
                    asm volatile("s_waitcnt vmcnt(0)" ::: "memory");
                }
            }
            if (qp == 3) asm volatile("s_waitcnt vmcnt(2)" ::: "memory");
            __builtin_amdgcn_s_barrier();
        }
        p ^= 1;
    }

    // epilogue: C/D layout col = lane&15, row = q*4 + reg  [m89-verified]
    float* Cb = C + (size_t)b * 1024 * NG + (size_t)bm0 * NG + bn0;
#pragma unroll
    for (int i = 0; i < NI; ++i)
#pragma unroll
        for (int j = 0; j < NJ; ++j)
#pragma unroll
            for (int r = 0; r < 4; ++r)
                Cb[(size_t)(wmL + i * 16 + q * 4 + r) * NG + wnL + j * 16 + mf] = acc[i][j][r];
}

// ---------------------------------------------------------------------------
// Barrier-free row softmax in place: one wave per row, 4 rows/block.
// ---------------------------------------------------------------------------
__global__ __launch_bounds__(256) void softmax_rows2(float* __restrict__ S) {
    const int t = threadIdx.x;
    const int wave = t >> 6, lane = t & 63;
    const size_t row = (size_t)blockIdx.x * 4 + wave;
    float* p = S + row * LK;
    f32x4 v[4];
#pragma unroll
    for (int c = 0; c < 4; ++c)
        v[c] = *(const f32x4*)(p + lane * 4 + c * 256);
    float m = -1e30f;
#pragma unroll
    for (int c = 0; c < 4; ++c)
        m = fmaxf(m, fmaxf(fmaxf(v[c][0], v[c][1]), fmaxf(v[c][2], v[c][3])));
#pragma unroll
    for (int off = 1; off < 64; off <<= 1) m = fmaxf(m, __shfl_xor(m, off, 64));
    float s = 0.0f;
#pragma unroll
    for (int c = 0; c < 4; ++c) {
        v[c][0] = __expf(v[c][0] - m);
        v[c][1] = __expf(v[c][1] - m);
        v[c][2] = __expf(v[c][2] - m);
        v[c][3] = __expf(v[c][3] - m);
        s += (v[c][0] + v[c][1]) + (v[c][2] + v[c][3]);
    }
#pragma unroll
    for (int off = 1; off < 64; off <<= 1) s += __shfl_xor(s, off, 64);
    const float inv = 1.0f / s;
#pragma unroll
    for (int c = 0; c < 4; ++c) {
        v[c] = v[c] * inv;
        *(f32x4*)(p + lane * 4 + c * 256) = v[c];
    }
}

// ===========================================================================
// Fallback A (ws >= 67 MB): round-4 verified 128x128 2-phase path
// ===========================================================================
template <int KG, int NG, int NPROD, bool PACKA>
__global__ __launch_bounds__(256) void gemm_bf16split(const float* __restrict__ A,
                                                      const float* __restrict__ B,
                                                      float* __restrict__ C) {
    __shared__ float sm[2][2][128 * 32];
    constexpr int GY  = NG / 128;
    constexpr int GYS = (GY == 8) ? 3 : 2;
    const u32 wgid = blockIdx.x + (blockIdx.y << 3) + ((u32)blockIdx.z << (3 + GYS));
    const u32 nwg  = (u32)(8 * GY * BATCH);
    const u32 swz  = (wgid & 7) * (nwg >> 3) + (wgid >> 3);
    const int bm0  = (swz & 7) * 128;
    const int bn0  = ((swz >> 3) & (GY - 1)) * 128;
    const int b    = swz >> (3 + GYS);
    const int tid = threadIdx.x;
    const int w   = tid >> 6;
    const int lane = tid & 63;
    const int op   = w >> 1;
    const int woff = (w & 1) * 64;
    const float* gsrc = (op == 0)
        ? A + (size_t)b * 1024 * KG + (size_t)(bm0 + woff) * KG
        : B + (size_t)b * NG * KG   + (size_t)(bn0 + woff) * KG;
    gsrc += (size_t)(lane >> 3) * KG + (size_t)(((lane & 7) ^ (lane >> 3)) * 4);
    const int mf = lane & 15, q = lane >> 4;
    const int e  = mf & 7;
    const int ch = ((q)     ^ e) * 4;
    const int cl = ((4 + q) ^ e) * 4;
    const int c0 = ((2 * q)     ^ e) * 4;
    const int c1 = ((2 * q + 1) ^ e) * 4;
    const int wm = (w & 1) * 64, wn = (w >> 1) * 64;
    f32x4 acc[4][4] = {};
    auto stage = [&](int pb, int k) {
#pragma unroll
        for (int t = 0; t < 8; ++t)
            __builtin_amdgcn_global_load_lds((const AS1 u32*)(gsrc + k + (size_t)t * 8 * KG),
                                             (AS3 u32*)(&sm[pb][op][(woff + t * 8) * 32]),
                                             16, 0, 0);
    };
    stage(0, 0);
    int p = 0;
    for (int k0 = 0; k0 < KG; k0 += 32) {
        __syncthreads();
        if (k0 + 32 < KG) stage(p ^ 1, k0 + 32);
        const float* As = &sm[p][0][0];
        const float* Bs = &sm[p][1][0];
        short8 ah[4], al[4], bh[4], bl[4];
#pragma unroll
        for (int i = 0; i < 4; ++i) {
            const int ra = (wm + mf + i * 16) * 32;
            if constexpr (PACKA) {
                ah[i] = *(const short8*)&As[ra + ch];
                if constexpr (NPROD == 3) al[i] = *(const short8*)&As[ra + cl];
            } else {
                f32x4 f0 = *(const f32x4*)&As[ra + c0];
                f32x4 f1 = *(const f32x4*)&As[ra + c1];
                if constexpr (NPROD == 3) mk_frags(f0, f1, ah[i], al[i]);
                else                      ah[i] = hi8(f0, f1);
            }
            const int rb = (wn + mf + i * 16) * 32;
            bh[i] = *(const short8*)&Bs[rb + ch];
            bl[i] = *(const short8*)&Bs[rb + cl];
        }
#pragma unroll
        for (int i = 0; i < 4; ++i)
#pragma unroll
            for (int j = 0; j < 4; ++j) {
                acc[i][j] = __builtin_amdgcn_mfma_f32_16x16x32_bf16(ah[i], bh[j], acc[i][j], 0, 0, 0);
                acc[i][j] = __builtin_amdgcn_mfma_f32_16x16x32_bf16(ah[i], bl[j], acc[i][j], 0, 0, 0);
                if constexpr (NPROD == 3)
                    acc[i][j] = __builtin_amdgcn_mfma_f32_16x16x32_bf16(al[i], bh[j], acc[i][j], 0, 0, 0);
            }
        p ^= 1;
    }
    float* Cb = C + (size_t)b * 1024 * NG + (size_t)bm0 * NG + bn0;
#pragma unroll
    for (int i = 0; i < 4; ++i)
#pragma unroll
        for (int j = 0; j < 4; ++j)
#pragma unroll
            for (int r = 0; r < 4; ++r)
                Cb[(size_t)(wm + i * 16 + q * 4 + r) * NG + wn + j * 16 + mf] = acc[i][j][r];
}

// ===========================================================================
// Fallback B (tiny ws): plain fp32 tiled GEMMs + block softmax
// ===========================================================================
constexpr int BMf = 64, BNf = 64, BKf = 16, PADf = 4;

__global__ __launch_bounds__(256) void softmax_rows(float* __restrict__ S) {
    float* p = S + (size_t)blockIdx.x * LK;
    const int t = threadIdx.x;
    float4 v = *(float4*)(p + (t << 2));
    float m = fmaxf(fmaxf(v.x, v.y), fmaxf(v.z, v.w));
#pragma unroll
    for (int off = 1; off < 64; off <<= 1) m = fmaxf(m, __shfl_xor(m, off, 64));
    __shared__ float redm[4]; __shared__ float reds[4];
    const int wave = t >> 6, lane = t & 63;
    if (lane == 0) redm[wave] = m;
    __syncthreads();
    m = fmaxf(fmaxf(redm[0], redm[1]), fmaxf(redm[2], redm[3]));
    v.x = __expf(v.x - m); v.y = __expf(v.y - m);
    v.z = __expf(v.z - m); v.w = __expf(v.w - m);
    float s = (v.x + v.y) + (v.z + v.w);
#pragma unroll
    for (int off = 1; off < 64; off <<= 1) s += __shfl_xor(s, off, 64);
    if (lane == 0) reds[wave] = s;
    __syncthreads();
    s = (reds[0] + reds[1]) + (reds[2] + reds[3]);
    const float inv = 1.0f / s;
    v.x *= inv; v.y *= inv; v.z *= inv; v.w *= inv;
    *(float4*)(p + (t << 2)) = v;
}

__global__ __launch_bounds__(256) void gemm_qvt(const float* __restrict__ Q,
                                                const float* __restrict__ V,
                                                float* __restrict__ S) {
    __shared__ __align__(16) float sA[BKf][BMf + PADf];
    __shared__ __align__(16) float sB[BKf][BNf + PADf];
    const int b = blockIdx.z;
    const float* Qb = Q + (size_t)b * LQ * DD + (size_t)blockIdx.x * BMf * DD;
    const float* Vb = V + (size_t)b * LK * DD + (size_t)blockIdx.y * BNf * DD;
    float*       Sb = S + (size_t)b * LQ * LK;
    const int tid = threadIdx.x;
    const int tx = tid & 15, ty = tid >> 4;
    const int lr = tid >> 2, lc = (tid & 3) << 2;
    float acc[4][4] = {};
    for (int k0 = 0; k0 < DD; k0 += BKf) {
        float4 qa = *(const float4*)(Qb + (size_t)lr * DD + k0 + lc);
        float4 va = *(const float4*)(Vb + (size_t)lr * DD + k0 + lc);
        __syncthreads();
        sA[lc + 0][lr] = qa.x; sA[lc + 1][lr] = qa.y; sA[lc + 2][lr] = qa.z; sA[lc + 3][lr] = qa.w;
        sB[lc + 0][lr] = va.x; sB[lc + 1][lr] = va.y; sB[lc + 2][lr] = va.z; sB[lc + 3][lr] = va.w;
        __syncthreads();
#pragma unroll
        for (int k = 0; k < BKf; ++k) {
            float4 a4 = *(const float4*)&sA[k][ty << 2];
            float4 b4 = *(const float4*)&sB[k][tx << 2];
            float a[4] = {a4.x, a4.y, a4.z, a4.w};
            float bb[4] = {b4.x, b4.y, b4.z, b4.w};
#pragma unroll
            for (int i = 0; i < 4; ++i)
#pragma unroll
                for (int j = 0; j < 4; ++j) acc[i][j] = fmaf(a[i], bb[j], acc[i][j]);
        }
    }
    const int r0 = blockIdx.x * BMf + (ty << 2), c0 = blockIdx.y * BNf + (tx << 2);
#pragma unroll
    for (int i = 0; i < 4; ++i) {
        float4 o = {acc[i][0], acc[i][1], acc[i][2], acc[i][3]};
        *(float4*)(Sb + (size_t)(r0 + i) * LK + c0) = o;
    }
}

__global__ __launch_bounds__(256) void gemm_pv(const float* __restrict__ P,
                                               const float* __restrict__ V,
                                               float* __restrict__ C) {
    __shared__ __align__(16) float sA[BKf][BMf + PADf];
    __shared__ __align__(16) float sB[BKf][BNf + PADf];
    const int b = blockIdx.z;
    const float* Pb = P + (size_t)b * LQ * LK + (size_t)blockIdx.x * BMf * LK;
    const float* Vb = V + (size_t)b * LK * DD;
    float*       Cb = C + (size_t)b * LQ * DD;
    const int tid = threadIdx.x;
    const int tx = tid & 15, ty = tid >> 4;
    const int lr = tid >> 2, lc = (tid & 3) << 2;
    const int bkr = tid >> 4, bcg = (tid & 15) << 2;
    const int n0 = blockIdx.y * BNf;
    float acc[4][4] = {};
    for (int k0 = 0; k0 < LK; k0 += BKf) {
        float4 pa = *(const float4*)(Pb + (size_t)lr * LK + k0 + lc);
        float4 vb = *(const float4*)(Vb + (size_t)(k0 + bkr) * DD + n0 + bcg);
        __syncthreads();
        sA[lc + 0][lr] = pa.x; sA[lc + 1][lr] = pa.y; sA[lc + 2][lr] = pa.z; sA[lc + 3][lr] = pa.w;
        *(float4*)&sB[bkr][bcg] = vb;
        __syncthreads();
#pragma unroll
        for (int k = 0; k < BKf; ++k) {
            float4 a4 = *(const float4*)&sA[k][ty << 2];
            float4 b4 = *(const float4*)&sB[k][tx << 2];
            float a[4] = {a4.x, a4.y, a4.z, a4.w};
            float bb[4] = {b4.x, b4.y, b4.z, b4.w};
#pragma unroll
            for (int i = 0; i < 4; ++i)
#pragma unroll
                for (int j = 0; j < 4; ++j) acc[i][j] = fmaf(a[i], bb[j], acc[i][j]);
        }
    }
    const int r0 = blockIdx.x * BMf + (ty << 2), c0 = n0 + (tx << 2);
#pragma unroll
    for (int i = 0; i < 4; ++i) {
        float4 o = {acc[i][0], acc[i][1], acc[i][2], acc[i][3]};
        *(float4*)(Cb + (size_t)(r0 + i) * DD + c0) = o;
    }
}

// ---------------------------------------------------------------------------
extern "C" void kernel_launch(void* const* d_in, const int* in_sizes, int n_in,
                              void* d_out, int out_size, void* d_ws, size_t ws_size,
                              hipStream_t stream) {
    const float* Q = (const float*)d_in[0];
    const float* V = (const float*)d_in[1];

    float* ctx  = (float*)d_out;                       // [16,1024,512]
    float* attn = ctx + (size_t)BATCH * LQ * DD;       // [16,1024,1024]

    const size_t qv_elems = (size_t)BATCH * LQ * DD;   // 8.4M floats = 33.55 MB
    const size_t need256  = 3 * qv_elems * sizeof(float);   // Qhl+Vhl+Vthl = 100.7 MB
    const size_t need128  = 2 * qv_elems * sizeof(float);   // Vhl+Vthl = 67.1 MB

    if (ws_size >= need256) {
        float* Qhl  = (float*)d_ws;
        float* Vhl  = Qhl + qv_elems;
        float* Vthl = Vhl + qv_elems;
        pack_q<<<dim3(BATCH * LQ * DD / (8 * 256)), 256, 0, stream>>>(Q, Qhl);
        transpose_pack_v<<<dim3(DD / 32, LK / 32, BATCH), 256, 0, stream>>>(V, Vhl, Vthl);
        // S = Q @ V^T : 256x256 tile, counted-vmcnt 4-phase, both packed
        gemm4ph<DD, LK, 256, 3, 1><<<dim3(4, 4, BATCH), 512, 0, stream>>>(Qhl, Vhl, attn);
        softmax_rows2<<<dim3(BATCH * LQ / 4), 256, 0, stream>>>(attn);
        // ctx = P @ V : 256x128 tile, A = attn fp32 (hi in-phase), 2-product
        gemm4ph<LK, DD, 128, 2, 0><<<dim3(4, 4, BATCH), 512, 0, stream>>>(attn, Vthl, ctx);
    } else if (ws_size >= need128) {
        float* Vhl  = (float*)d_ws;
        float* Vthl = Vhl + qv_elems;
        transpose_pack_v<<<dim3(DD / 32, LK / 32, BATCH), 256, 0, stream>>>(V, Vhl, Vthl);
        gemm_bf16split<DD, LK, 3, false><<<dim3(8, 8, BATCH), 256, 0, stream>>>(Q, Vhl, attn);
        softmax_rows2<<<dim3(BATCH * LQ / 4), 256, 0, stream>>>(attn);
        gemm_bf16split<LK, DD, 2, false><<<dim3(8, 4, BATCH), 256, 0, stream>>>(attn, Vthl, ctx);
    } else {
        gemm_qvt<<<dim3(LQ / BMf, LK / BNf, BATCH), 256, 0, stream>>>(Q, V, attn);
        softmax_rows<<<dim3(BATCH * LQ), 256, 0, stream>>>(attn);
        gemm_pv<<<dim3(LQ / BMf, DD / BNf, BATCH), 256, 0, stream>>>(attn, V, ctx);
    }
}